// Round 9
// baseline (73.288 us; speedup 1.0000x reference)
//
#include <hip/hip_runtime.h>
#include <hip/hip_bf16.h>

typedef __attribute__((ext_vector_type(8))) short short8;
typedef __attribute__((ext_vector_type(4))) float f32x4;
typedef _Float16 __attribute__((ext_vector_type(2))) half2v;

#define INV_TEMP 14.285714285714286f
#define LOGIT_MAX 14.2857143f
#define L2E 1.44269504f
#define OFFE (LOGIT_MAX * L2E)

__device__ __forceinline__ ushort bf16c(float f) {
  uint u = __float_as_uint(f);
  uint r = (u + 0x7fffu + ((u >> 16) & 1u)) >> 16;
  return (ushort)r;
}
__device__ __forceinline__ uint pk2(float a, float b) {
  return (uint)bf16c(a) | ((uint)bf16c(b) << 16);
}
__device__ __forceinline__ uint pkh(float a, float b) {
  return __builtin_bit_cast(uint, __builtin_amdgcn_cvt_pkrtz(a, b));
}
__device__ __forceinline__ half2v h2(uint u) {
  return __builtin_bit_cast(half2v, u);
}
__device__ __forceinline__ int sdot4_(uint a, uint b, int c) {
  return __builtin_amdgcn_sdot4((int)a, (int)b, c, false);
}

template <int CTRL>
__device__ __forceinline__ float dpp_add(float v) {
  const int x = __builtin_amdgcn_mov_dpp(__float_as_int(v), CTRL, 0xF, 0xF, true);
  return v + __int_as_float(x);
}
template <int CTRL>
__device__ __forceinline__ float dpp_max(float v) {
  const int x = __builtin_amdgcn_mov_dpp(__float_as_int(v), CTRL, 0xF, 0xF, true);
  return fmaxf(v, __int_as_float(x));
}
template <int CTRL>
__device__ __forceinline__ int dpp_addi(int v) {
  return v + __builtin_amdgcn_mov_dpp(v, CTRL, 0xF, 0xF, true);
}
__device__ __forceinline__ float qsum16(float v) {
  v = dpp_add<0xB1>(v);
  v = dpp_add<0x4E>(v);
  v = dpp_add<0x141>(v);
  v = dpp_add<0x140>(v);
  return v;
}
__device__ __forceinline__ int qsum8i(int v) {
  v = dpp_addi<0xB1>(v);
  v = dpp_addi<0x4E>(v);
  v = dpp_addi<0x141>(v);
  return v;
}

// ---------- fp32 -> bf16 for ctx (blocks [0,512)) and W (blocks [512,1280)) ----------
__global__ __launch_bounds__(256) void cvt_bf16_kernel(
    const float* __restrict__ ctx, const float* __restrict__ W,
    ushort* __restrict__ ctxb, ushort* __restrict__ Wb) {
  const int bid = blockIdx.x;
  const float* in;
  ushort* out;
  size_t i;
  if (bid < 512) { in = ctx; out = ctxb; i = (size_t)bid * 256 + threadIdx.x; }
  else           { in = W;   out = Wb;   i = (size_t)(bid - 512) * 256 + threadIdx.x; }
  const float4 a = *(const float4*)(in + i * 8);
  const float4 b = *(const float4*)(in + i * 8 + 4);
  const uint4 o = make_uint4(pk2(a.x, a.y), pk2(a.z, a.w), pk2(b.x, b.y), pk2(b.z, b.w));
  *(uint4*)(out + i * 8) = o;
}

// ---------- pool -> int4 biased (p' = q+8, q = rint(e/s_r), s_r = rowmax/7) ----------
// Row = 128 B = 32 uints; nibble n of uint j = chan 8j+n. scale[r] = s_r (f32).
// Also zeroes acc[0..11].
__global__ __launch_bounds__(256) void pool_norm_kernel(
    const float* __restrict__ enc, uint* __restrict__ pool4,
    float* __restrict__ scale, float* __restrict__ acc) {
  const int tid = threadIdx.x;
  if (blockIdx.x == 0 && tid < 12) acc[tid] = 0.f;
  const int grp = tid >> 4, lane = tid & 15;
  const int r = blockIdx.x * 16 + grp;  // 0..2047
  const float* src = enc + (size_t)r * 256 + lane * 16;
  float4 v0 = *(const float4*)(src);
  float4 v1 = *(const float4*)(src + 4);
  float4 v2 = *(const float4*)(src + 8);
  float4 v3 = *(const float4*)(src + 12);
  float c[16] = {v0.x, v0.y, v0.z, v0.w, v1.x, v1.y, v1.z, v1.w,
                 v2.x, v2.y, v2.z, v2.w, v3.x, v3.y, v3.z, v3.w};
  float ss = 0.f;
#pragma unroll
  for (int i = 0; i < 16; ++i) ss = fmaf(c[i], c[i], ss);
  ss = qsum16(ss);
  const float inv = rsqrtf(ss);
  float am = 0.f;
#pragma unroll
  for (int i = 0; i < 16; ++i) {
    c[i] *= inv;
    am = fmaxf(am, fabsf(c[i]));
  }
  am = dpp_max<0xB1>(am); am = dpp_max<0x4E>(am);
  am = dpp_max<0x141>(am); am = dpp_max<0x140>(am);
  const float qs = 7.f / am;
  uint w0 = 0, w1 = 0;
#pragma unroll
  for (int n = 0; n < 8; ++n) {
    w0 |= (uint)((int)rintf(c[n] * qs) + 8) << (4 * n);
    w1 |= (uint)((int)rintf(c[8 + n] * qs) + 8) << (4 * n);
  }
  *(uint2*)(pool4 + (size_t)r * 32 + lane * 2) = make_uint2(w0, w1);
  if (lane == 0) scale[r] = am * (1.f / 7.f);
}

// ---------- z_hat[k] = ctx_rows @ W[k]^T via bf16 MFMA, BK=64, f16-pair out ----------
__global__ __launch_bounds__(256) void zhat_gemm_kernel(
    const ushort* __restrict__ ctxb, const ushort* __restrict__ Wb,
    uint* __restrict__ Zp) {
  const int kk = blockIdx.z;
  const int Tk = 255 - kk, Nk = 8 * Tk;
  const int rowbase = blockIdx.y * 64;
  if (rowbase >= Nk) return;
  const int colbase = blockIdx.x * 128;

  __shared__ ushort As[64 * 72];   // row stride 72 (144 B): 2-lanes/bank on reads
  __shared__ ushort Bs[128 * 72];

  const int tid = threadIdx.x;
  const int arow = tid & 63;
  const int akseg = (tid >> 6) * 8;     // {0,8,16,24}; +32 for second half
  int n = rowbase + arow;
  if (n >= Nk) n = Nk - 1;
  const int bb = n / Tk, tt = n - bb * Tk;
  const ushort* aptr = ctxb + ((size_t)(bb * 256 + tt)) * 512 + akseg;
  const int brow = tid & 127;
  const int bk0 = (tid >> 7) * 8;       // {0,8}; +16/+32/+48 strided
  const ushort* bptr = Wb + ((size_t)kk * 256 + colbase + brow) * 512 + bk0;

  const int wid = tid >> 6, lane = tid & 63;
  const int wm = wid >> 1, wn = wid & 1;
  const int l15 = lane & 15, l16 = lane >> 4;

  f32x4 acc[2][4];
#pragma unroll
  for (int i = 0; i < 2; ++i)
#pragma unroll
    for (int j = 0; j < 4; ++j) acc[i][j] = (f32x4){0.f, 0.f, 0.f, 0.f};

  const ushort* aread = &As[(wm * 32 + l15) * 72 + l16 * 8];
  const ushort* bread = &Bs[(wn * 64 + l15) * 72 + l16 * 8];

  for (int k0 = 0; k0 < 512; k0 += 64) {
    const uint4 av0 = *(const uint4*)(aptr + k0);
    const uint4 av1 = *(const uint4*)(aptr + k0 + 32);
    const uint4 bv0 = *(const uint4*)(bptr + k0);
    const uint4 bv1 = *(const uint4*)(bptr + k0 + 16);
    const uint4 bv2 = *(const uint4*)(bptr + k0 + 32);
    const uint4 bv3 = *(const uint4*)(bptr + k0 + 48);
    __syncthreads();
    *(uint4*)&As[arow * 72 + akseg]      = av0;
    *(uint4*)&As[arow * 72 + akseg + 32] = av1;
    *(uint4*)&Bs[brow * 72 + bk0]      = bv0;
    *(uint4*)&Bs[brow * 72 + bk0 + 16] = bv1;
    *(uint4*)&Bs[brow * 72 + bk0 + 32] = bv2;
    *(uint4*)&Bs[brow * 72 + bk0 + 48] = bv3;
    __syncthreads();
#pragma unroll
    for (int ks = 0; ks < 64; ks += 32) {
      short8 bf[4];
#pragma unroll
      for (int nb = 0; nb < 4; ++nb) bf[nb] = *(const short8*)(bread + nb * 16 * 72 + ks);
#pragma unroll
      for (int mb = 0; mb < 2; ++mb) {
        short8 af = *(const short8*)(aread + mb * 16 * 72 + ks);
#pragma unroll
        for (int nb = 0; nb < 4; ++nb)
          acc[mb][nb] = __builtin_amdgcn_mfma_f32_16x16x32_bf16(af, bf[nb], acc[mb][nb], 0, 0, 0);
      }
    }
  }

  // uint u of row holds chans (32*(u>>4)+(u&15), +16)
#pragma unroll
  for (int mb = 0; mb < 2; ++mb) {
    const int row0 = rowbase + wm * 32 + mb * 16 + l16 * 4;
#pragma unroll
    for (int r = 0; r < 4; ++r) {
      const int row = row0 + r;
      if (row < Nk) {
        uint* zp = Zp + ((size_t)kk * 2040 + row) * 128 + (colbase >> 1) + wn * 32 + l15;
        zp[0]  = pkh(acc[mb][0][r], acc[mb][1][r]);
        zp[16] = pkh(acc[mb][2][r], acc[mb][3][r]);
      }
    }
  }
}

// ---------- loss: 16 lanes/row = 2 neg-halves x 8 chan-lanes; int8 z · int4 pool ----------
// zq[0..3] = bytes for chans 8t+{0,2,4,6} (even nibbles), zq[4..7] = odd nibbles.
#define DOTN(P) ({                                                              \
    int d0_ = 0, d1_ = 0;                                                       \
    uint e_, o_;                                                                \
    e_ = P.x & 0x0F0F0F0Fu; o_ = (P.x >> 4) & 0x0F0F0F0Fu;                      \
    d0_ = sdot4_(zq[0], e_, d0_); d1_ = sdot4_(zq[4], o_, d1_);                 \
    e_ = P.y & 0x0F0F0F0Fu; o_ = (P.y >> 4) & 0x0F0F0F0Fu;                      \
    d0_ = sdot4_(zq[1], e_, d0_); d1_ = sdot4_(zq[5], o_, d1_);                 \
    e_ = P.z & 0x0F0F0F0Fu; o_ = (P.z >> 4) & 0x0F0F0F0Fu;                      \
    d0_ = sdot4_(zq[2], e_, d0_); d1_ = sdot4_(zq[6], o_, d1_);                 \
    e_ = P.w & 0x0F0F0F0Fu; o_ = (P.w >> 4) & 0x0F0F0F0Fu;                      \
    d0_ = sdot4_(zq[3], e_, d0_); d1_ = sdot4_(zq[7], o_, d1_);                 \
    qsum8i(d0_ + d1_); })

#define LDB(P, S, IDX) { P = *(const uint4*)(pbase + (size_t)(uint)(IDX) * 32); \
                         S = scale[(uint)(IDX)]; }
// logit_e = (D' - 8Z)*s_r*km - OFFE = D'*(s_r*km) + (s_r*c2 - OFFE)
#define ACCB(SUM, P, S)                                                         \
  SUM += exp2f(fmaf((float)DOTN(P), S * km, fmaf(S, c2, -OFFE)));

__global__ __launch_bounds__(256) void loss_kernel(
    const uint* __restrict__ Zp, const uint* __restrict__ pool4,
    const float* __restrict__ scale, const int* __restrict__ neg_idx,
    float* __restrict__ acc) {
  const int kk = blockIdx.y;
  const int Tk = 255 - kk, Nk = 8 * Tk;
  if ((int)(blockIdx.x * 16) >= Nk) return;
  const int tid = threadIdx.x;
  const int n = blockIdx.x * 16 + (tid >> 4);
  const int l = tid & 15;
  const int h = l >> 3;   // neg half: negs [64h, 64h+64)
  const int g = l & 7;    // chan chunk: chans [32g, 32g+32)
  float row_loss = 0.f;
  if (n < Nk) {
    // lane's chans [32g,32g+32) = Zp uints [16g,16g+16): lo -> +0..15, hi -> +16..31
    const uint* zr = Zp + ((size_t)kk * 2040 + n) * 128 + g * 16;
    uint zu[16];
#pragma unroll
    for (int i = 0; i < 4; ++i) *(uint4*)(zu + 4 * i) = *(const uint4*)(zr + 4 * i);
    float zf[32];
#pragma unroll
    for (int c = 0; c < 16; ++c) {
      const half2v hv = h2(zu[c]);
      zf[c] = (float)hv.x;
      zf[16 + c] = (float)hv.y;
    }
    float ss = 0.f;
#pragma unroll
    for (int i = 0; i < 32; ++i) ss = fmaf(zf[i], zf[i], ss);
    ss = dpp_add<0xB1>(ss); ss = dpp_add<0x4E>(ss); ss = dpp_add<0x141>(ss);
    const float s127 = rsqrtf(ss) * 127.f;
    uint zq[8];
#pragma unroll
    for (int t = 0; t < 4; ++t) {
      const uint e0 = (uint)((int)rintf(zf[8 * t]     * s127) & 255);
      const uint e1 = (uint)((int)rintf(zf[8 * t + 2] * s127) & 255);
      const uint e2 = (uint)((int)rintf(zf[8 * t + 4] * s127) & 255);
      const uint e3 = (uint)((int)rintf(zf[8 * t + 6] * s127) & 255);
      zq[t] = e0 | (e1 << 8) | (e2 << 16) | (e3 << 24);
      const uint o0 = (uint)((int)rintf(zf[8 * t + 1] * s127) & 255);
      const uint o1 = (uint)((int)rintf(zf[8 * t + 3] * s127) & 255);
      const uint o2 = (uint)((int)rintf(zf[8 * t + 5] * s127) & 255);
      const uint o3 = (uint)((int)rintf(zf[8 * t + 7] * s127) & 255);
      zq[t + 4] = o0 | (o1 << 8) | (o2 << 16) | (o3 << 24);
    }
    int nq = 0, zs = 0;
#pragma unroll
    for (int t = 0; t < 8; ++t) {
      nq = sdot4_(zq[t], zq[t], nq);
      zs = sdot4_(zq[t], 0x01010101u, zs);
    }
    nq = qsum8i(nq);
    zs = qsum8i(zs);
    const float km = (INV_TEMP * L2E) * rsqrtf((float)nq);
    const float c2 = -8.f * (float)zs * km;

    const uint* pbase = pool4 + g * 4;
    const int bb = n / Tk, tt = n - bb * Tk;
    uint4 PP; float SP;
    LDB(PP, SP, bb * 256 + tt + kk + 1)
    const float pose = fmaf((float)DOTN(PP), SP * km, SP * c2);

    // this half's 64 negs, 4+4 double-buffered
    const int* ip = neg_idx + ((size_t)kk * 2040 + n) * 128 + h * 64;
    float s0 = 0.f, s1 = 0.f, s2 = 0.f, s3 = 0.f;
    uint4 A, B, C, D, E, F, G, H;
    float As_, Bs_, Cs_, Ds_, Es_, Fs_, Gs_, Hs_;
    {
      const int4 iv = *(const int4*)ip;
      LDB(A, As_, iv.x) LDB(B, Bs_, iv.y) LDB(C, Cs_, iv.z) LDB(D, Ds_, iv.w)
    }
    for (int j8 = 0; j8 < 8; ++j8) {
      {  // prefetch odd quad
        const int4 jv = *(const int4*)(ip + j8 * 8 + 4);
        LDB(E, Es_, jv.x) LDB(F, Fs_, jv.y) LDB(G, Gs_, jv.z) LDB(H, Hs_, jv.w)
      }
      ACCB(s0, A, As_) ACCB(s1, B, Bs_) ACCB(s2, C, Cs_) ACCB(s3, D, Ds_)
      if (j8 < 7) {  // prefetch next even quad
        const int4 kv = *(const int4*)(ip + j8 * 8 + 8);
        LDB(A, As_, kv.x) LDB(B, Bs_, kv.y) LDB(C, Cs_, kv.z) LDB(D, Ds_, kv.w)
      }
      ACCB(s0, E, Es_) ACCB(s1, F, Fs_) ACCB(s2, G, Gs_) ACCB(s3, H, Hs_)
    }
    // combine the two halves: row_mirror crosses (h,g)<->(1-h,7-g)
    float sl = (s0 + s1) + (s2 + s3);
    sl = dpp_add<0x140>(sl);
    const float ssum = sl + exp2f(pose - OFFE);
    row_loss = LOGIT_MAX + 0.69314718f * (__log2f(ssum) - pose);
  }
  __shared__ float bl[16];
  if (l == 0) bl[tid >> 4] = row_loss;
  __syncthreads();
  if (tid == 0) {
    float s = 0.f;
#pragma unroll
    for (int i = 0; i < 16; ++i) s += bl[i];
    atomicAdd(&acc[kk], s);
  }
}

__global__ void finalize_kernel(const float* __restrict__ acc,
                                float* __restrict__ out) {
  if (threadIdx.x == 0) {
    float tot = 0.f;
#pragma unroll
    for (int kk = 0; kk < 12; ++kk) tot += acc[kk] / (8.0f * (255 - kk));
    out[0] = tot / 12.0f;
  }
}

extern "C" void kernel_launch(void* const* d_in, const int* in_sizes, int n_in,
                              void* d_out, int out_size, void* d_ws, size_t ws_size,
                              hipStream_t stream) {
  const float* ctx = (const float*)d_in[0];   // (8,256,512)
  const float* enc = (const float*)d_in[1];   // (8,256,256)
  const float* W   = (const float*)d_in[2];   // (12,256,512)
  const int*   neg = (const int*)d_in[3];     // (12,2040,128)
  float* out = (float*)d_out;

  char* ws = (char*)d_ws;
  uint*   pool4 = (uint*)(ws);                      // 2048*128 B  = 262,144
  float*  scale = (float*)(ws + 262144);            // 2048*4     = 8,192
  ushort* ctxb  = (ushort*)(ws + 270336);           // 2,097,152
  ushort* Wb    = (ushort*)(ws + 2367488);          // 3,145,728
  uint*   Zp    = (uint*)(ws + 5513216);            // 12,533,760
  float*  accb  = (float*)(ws + 18046976);          // 48 B

  cvt_bf16_kernel<<<dim3(1280), dim3(256), 0, stream>>>(ctx, W, ctxb, Wb);
  pool_norm_kernel<<<dim3(128), dim3(256), 0, stream>>>(enc, pool4, scale, accb);
  zhat_gemm_kernel<<<dim3(2, 32, 12), dim3(256), 0, stream>>>(ctxb, Wb, Zp);
  loss_kernel<<<dim3(128, 12), dim3(256), 0, stream>>>(Zp, pool4, scale, neg, accb);
  finalize_kernel<<<dim3(1), dim3(64), 0, stream>>>(accb, out);
}

// Round 10
// 69.190 us; speedup vs baseline: 1.0592x; 1.0592x over previous
//
#include <hip/hip_runtime.h>
#include <hip/hip_bf16.h>

typedef __attribute__((ext_vector_type(8))) short short8;
typedef __attribute__((ext_vector_type(4))) float f32x4;
typedef _Float16 __attribute__((ext_vector_type(2))) half2v;

#define INV_TEMP 14.285714285714286f
#define LOGIT_MAX 14.2857143f
#define L2E 1.44269504f
#define OFFE (LOGIT_MAX * L2E)
#define PCLIP 0.23f
#define PDELTA (PCLIP / 7.f)
#define PQS (7.f / PCLIP)

__device__ __forceinline__ ushort bf16c(float f) {
  uint u = __float_as_uint(f);
  uint r = (u + 0x7fffu + ((u >> 16) & 1u)) >> 16;
  return (ushort)r;
}
__device__ __forceinline__ uint pk2(float a, float b) {
  return (uint)bf16c(a) | ((uint)bf16c(b) << 16);
}
__device__ __forceinline__ uint pkh(float a, float b) {
  return __builtin_bit_cast(uint, __builtin_amdgcn_cvt_pkrtz(a, b));
}
__device__ __forceinline__ half2v h2(uint u) {
  return __builtin_bit_cast(half2v, u);
}
__device__ __forceinline__ int sdot4_(uint a, uint b, int c) {
  return __builtin_amdgcn_sdot4((int)a, (int)b, c, false);
}

template <int CTRL>
__device__ __forceinline__ float dpp_add(float v) {
  const int x = __builtin_amdgcn_mov_dpp(__float_as_int(v), CTRL, 0xF, 0xF, true);
  return v + __int_as_float(x);
}
template <int CTRL>
__device__ __forceinline__ int dpp_addi(int v) {
  return v + __builtin_amdgcn_mov_dpp(v, CTRL, 0xF, 0xF, true);
}
__device__ __forceinline__ float qsum16(float v) {
  v = dpp_add<0xB1>(v);
  v = dpp_add<0x4E>(v);
  v = dpp_add<0x141>(v);
  v = dpp_add<0x140>(v);
  return v;
}
__device__ __forceinline__ int qsum8i(int v) {
  v = dpp_addi<0xB1>(v);
  v = dpp_addi<0x4E>(v);
  v = dpp_addi<0x141>(v);
  return v;
}

// ---------- fp32 -> bf16 for ctx (blocks [0,512)) and W (blocks [512,1280)) ----------
__global__ __launch_bounds__(256) void cvt_bf16_kernel(
    const float* __restrict__ ctx, const float* __restrict__ W,
    ushort* __restrict__ ctxb, ushort* __restrict__ Wb) {
  const int bid = blockIdx.x;
  const float* in;
  ushort* out;
  size_t i;
  if (bid < 512) { in = ctx; out = ctxb; i = (size_t)bid * 256 + threadIdx.x; }
  else           { in = W;   out = Wb;   i = (size_t)(bid - 512) * 256 + threadIdx.x; }
  const float4 a = *(const float4*)(in + i * 8);
  const float4 b = *(const float4*)(in + i * 8 + 4);
  const uint4 o = make_uint4(pk2(a.x, a.y), pk2(a.z, a.w), pk2(b.x, b.y), pk2(b.z, b.w));
  *(uint4*)(out + i * 8) = o;
}

// ---------- pool -> int4 biased, GLOBAL scale: p' = clamp(rint(e/PDELTA),-7,7)+8 ----------
// Row = 128 B = 32 uints; nibble n of uint j = chan 8j+n. Also zeroes acc[0..11].
__global__ __launch_bounds__(256) void pool_norm_kernel(
    const float* __restrict__ enc, uint* __restrict__ pool4,
    float* __restrict__ acc) {
  const int tid = threadIdx.x;
  if (blockIdx.x == 0 && tid < 12) acc[tid] = 0.f;
  const int grp = tid >> 4, lane = tid & 15;
  const int r = blockIdx.x * 16 + grp;  // 0..2047
  const float* src = enc + (size_t)r * 256 + lane * 16;
  float4 v0 = *(const float4*)(src);
  float4 v1 = *(const float4*)(src + 4);
  float4 v2 = *(const float4*)(src + 8);
  float4 v3 = *(const float4*)(src + 12);
  float c[16] = {v0.x, v0.y, v0.z, v0.w, v1.x, v1.y, v1.z, v1.w,
                 v2.x, v2.y, v2.z, v2.w, v3.x, v3.y, v3.z, v3.w};
  float ss = 0.f;
#pragma unroll
  for (int i = 0; i < 16; ++i) ss = fmaf(c[i], c[i], ss);
  ss = qsum16(ss);
  const float qs = rsqrtf(ss) * PQS;
  uint w0 = 0, w1 = 0;
#pragma unroll
  for (int n = 0; n < 8; ++n) {
    const int q0 = (int)rintf(fminf(fmaxf(c[n] * qs, -7.f), 7.f)) + 8;
    const int q1 = (int)rintf(fminf(fmaxf(c[8 + n] * qs, -7.f), 7.f)) + 8;
    w0 |= (uint)q0 << (4 * n);
    w1 |= (uint)q1 << (4 * n);
  }
  *(uint2*)(pool4 + (size_t)r * 32 + lane * 2) = make_uint2(w0, w1);
}

// ---------- z_hat[k] = ctx_rows @ W[k]^T via bf16 MFMA, f16-pair out (r8 proven) ----------
__global__ __launch_bounds__(256) void zhat_gemm_kernel(
    const ushort* __restrict__ ctxb, const ushort* __restrict__ Wb,
    uint* __restrict__ Zp) {
  const int kk = blockIdx.z;
  const int Tk = 255 - kk, Nk = 8 * Tk;
  const int rowbase = blockIdx.y * 64;
  if (rowbase >= Nk) return;
  const int colbase = blockIdx.x * 128;

  __shared__ ushort As[64 * 40];
  __shared__ ushort Bs[128 * 40];

  const int tid = threadIdx.x;
  const int arow = tid & 63;
  const int akseg = (tid >> 6) * 8;
  int n = rowbase + arow;
  if (n >= Nk) n = Nk - 1;
  const int bb = n / Tk, tt = n - bb * Tk;
  const ushort* aptr = ctxb + ((size_t)(bb * 256 + tt)) * 512 + akseg;
  const int brow = tid & 127;
  const int bk0 = (tid >> 7) * 8;
  const ushort* bptr = Wb + ((size_t)kk * 256 + colbase + brow) * 512 + bk0;

  const int wid = tid >> 6, lane = tid & 63;
  const int wm = wid >> 1, wn = wid & 1;
  const int l15 = lane & 15, l16 = lane >> 4;

  f32x4 acc[2][4];
#pragma unroll
  for (int i = 0; i < 2; ++i)
#pragma unroll
    for (int j = 0; j < 4; ++j) acc[i][j] = (f32x4){0.f, 0.f, 0.f, 0.f};

  const ushort* aread = &As[(wm * 32 + l15) * 40 + l16 * 8];
  const ushort* bread = &Bs[(wn * 64 + l15) * 40 + l16 * 8];

  for (int k0 = 0; k0 < 512; k0 += 32) {
    const uint4 av = *(const uint4*)(aptr + k0);
    const uint4 bv0 = *(const uint4*)(bptr + k0);
    const uint4 bv1 = *(const uint4*)(bptr + k0 + 16);
    __syncthreads();
    *(uint4*)&As[arow * 40 + akseg] = av;
    *(uint4*)&Bs[brow * 40 + bk0] = bv0;
    *(uint4*)&Bs[brow * 40 + bk0 + 16] = bv1;
    __syncthreads();
    short8 bf[4];
#pragma unroll
    for (int nb = 0; nb < 4; ++nb) bf[nb] = *(const short8*)(bread + nb * 16 * 40);
#pragma unroll
    for (int mb = 0; mb < 2; ++mb) {
      short8 af = *(const short8*)(aread + mb * 16 * 40);
#pragma unroll
      for (int nb = 0; nb < 4; ++nb)
        acc[mb][nb] = __builtin_amdgcn_mfma_f32_16x16x32_bf16(af, bf[nb], acc[mb][nb], 0, 0, 0);
    }
  }

  // uint u of row holds chans (32*(u>>4)+(u&15), +16)
#pragma unroll
  for (int mb = 0; mb < 2; ++mb) {
    const int row0 = rowbase + wm * 32 + mb * 16 + l16 * 4;
#pragma unroll
    for (int r = 0; r < 4; ++r) {
      const int row = row0 + r;
      if (row < Nk) {
        uint* zp = Zp + ((size_t)kk * 2040 + row) * 128 + (colbase >> 1) + wn * 32 + l15;
        zp[0]  = pkh(acc[mb][0][r], acc[mb][1][r]);
        zp[16] = pkh(acc[mb][2][r], acc[mb][3][r]);
      }
    }
  }
}

// ---------- loss: 16 lanes/row = 2 neg-halves x 8 chan-lanes; int8 z · int4 pool ----------
// zq[0..3] = bytes for chans 8t+{0,2,4,6} (even nibbles), zq[4..7] = odd nibbles.
#define DOTN(P) ({                                                              \
    int d0_ = 0, d1_ = 0;                                                       \
    uint e_, o_;                                                                \
    e_ = P.x & 0x0F0F0F0Fu; o_ = (P.x >> 4) & 0x0F0F0F0Fu;                      \
    d0_ = sdot4_(zq[0], e_, d0_); d1_ = sdot4_(zq[4], o_, d1_);                 \
    e_ = P.y & 0x0F0F0F0Fu; o_ = (P.y >> 4) & 0x0F0F0F0Fu;                      \
    d0_ = sdot4_(zq[1], e_, d0_); d1_ = sdot4_(zq[5], o_, d1_);                 \
    e_ = P.z & 0x0F0F0F0Fu; o_ = (P.z >> 4) & 0x0F0F0F0Fu;                      \
    d0_ = sdot4_(zq[2], e_, d0_); d1_ = sdot4_(zq[6], o_, d1_);                 \
    e_ = P.w & 0x0F0F0F0Fu; o_ = (P.w >> 4) & 0x0F0F0F0Fu;                      \
    d0_ = sdot4_(zq[3], e_, d0_); d1_ = sdot4_(zq[7], o_, d1_);                 \
    qsum8i(d0_ + d1_); })

#define LDB(P, IDX) P = *(const uint4*)(pbase + (size_t)(uint)(IDX) * 32);
// logit_e(base2) = D'*kG + c2 - OFFE  (c2m = c2 - OFFE precomputed)
#define ACCB(SUM, P) SUM += exp2f(fmaf((float)DOTN(P), kG, c2m));

__global__ __launch_bounds__(256) void loss_kernel(
    const uint* __restrict__ Zp, const uint* __restrict__ pool4,
    const int* __restrict__ neg_idx, float* __restrict__ acc) {
  const int kk = blockIdx.y;
  const int Tk = 255 - kk, Nk = 8 * Tk;
  if ((int)(blockIdx.x * 16) >= Nk) return;
  const int tid = threadIdx.x;
  const int n = blockIdx.x * 16 + (tid >> 4);
  const int l = tid & 15;
  const int h = l >> 3;   // neg half: negs [64h, 64h+64)
  const int g = l & 7;    // chan chunk: chans [32g, 32g+32)
  float row_loss = 0.f;
  if (n < Nk) {
    // lane's chans [32g,32g+32) = Zp uints [16g,16g+16): lo -> +0..15, hi -> +16..31
    const uint* zr = Zp + ((size_t)kk * 2040 + n) * 128 + g * 16;
    uint zu[16];
#pragma unroll
    for (int i = 0; i < 4; ++i) *(uint4*)(zu + 4 * i) = *(const uint4*)(zr + 4 * i);
    float zf[32];
#pragma unroll
    for (int c = 0; c < 16; ++c) {
      const half2v hv = h2(zu[c]);
      zf[c] = (float)hv.x;
      zf[16 + c] = (float)hv.y;
    }
    float ss = 0.f;
#pragma unroll
    for (int i = 0; i < 32; ++i) ss = fmaf(zf[i], zf[i], ss);
    ss = dpp_add<0xB1>(ss); ss = dpp_add<0x4E>(ss); ss = dpp_add<0x141>(ss);
    const float s127 = rsqrtf(ss) * 127.f;
    uint zq[8];
#pragma unroll
    for (int t = 0; t < 4; ++t) {
      const uint e0 = (uint)((int)rintf(zf[8 * t]     * s127) & 255);
      const uint e1 = (uint)((int)rintf(zf[8 * t + 2] * s127) & 255);
      const uint e2 = (uint)((int)rintf(zf[8 * t + 4] * s127) & 255);
      const uint e3 = (uint)((int)rintf(zf[8 * t + 6] * s127) & 255);
      zq[t] = e0 | (e1 << 8) | (e2 << 16) | (e3 << 24);
      const uint o0 = (uint)((int)rintf(zf[8 * t + 1] * s127) & 255);
      const uint o1 = (uint)((int)rintf(zf[8 * t + 3] * s127) & 255);
      const uint o2 = (uint)((int)rintf(zf[8 * t + 5] * s127) & 255);
      const uint o3 = (uint)((int)rintf(zf[8 * t + 7] * s127) & 255);
      zq[t + 4] = o0 | (o1 << 8) | (o2 << 16) | (o3 << 24);
    }
    int nq = 0, zs = 0;
#pragma unroll
    for (int t = 0; t < 8; ++t) {
      nq = sdot4_(zq[t], zq[t], nq);
      zs = sdot4_(zq[t], 0x01010101u, zs);
    }
    nq = qsum8i(nq);
    zs = qsum8i(zs);
    const float kG = (INV_TEMP * L2E * PDELTA) * rsqrtf((float)nq);
    const float c2 = -8.f * (float)zs * kG;
    const float c2m = c2 - OFFE;

    const uint* pbase = pool4 + g * 4;
    const int bb = n / Tk, tt = n - bb * Tk;
    uint4 PP;
    LDB(PP, bb * 256 + tt + kk + 1)
    const float pose = fmaf((float)DOTN(PP), kG, c2);

    // this half's 64 negs, 4+4 double-buffered
    const int* ip = neg_idx + ((size_t)kk * 2040 + n) * 128 + h * 64;
    float s0 = 0.f, s1 = 0.f, s2 = 0.f, s3 = 0.f;
    uint4 A, B, C, D, E, F, G, H;
    {
      const int4 iv = *(const int4*)ip;
      LDB(A, iv.x) LDB(B, iv.y) LDB(C, iv.z) LDB(D, iv.w)
    }
    for (int j8 = 0; j8 < 8; ++j8) {
      {  // prefetch odd quad
        const int4 jv = *(const int4*)(ip + j8 * 8 + 4);
        LDB(E, jv.x) LDB(F, jv.y) LDB(G, jv.z) LDB(H, jv.w)
      }
      ACCB(s0, A) ACCB(s1, B) ACCB(s2, C) ACCB(s3, D)
      if (j8 < 7) {  // prefetch next even quad
        const int4 kv = *(const int4*)(ip + j8 * 8 + 8);
        LDB(A, kv.x) LDB(B, kv.y) LDB(C, kv.z) LDB(D, kv.w)
      }
      ACCB(s0, E) ACCB(s1, F) ACCB(s2, G) ACCB(s3, H)
    }
    // combine the two halves: row_mirror crosses (h,g)<->(1-h,7-g)
    float sl = (s0 + s1) + (s2 + s3);
    sl = dpp_add<0x140>(sl);
    const float ssum = sl + exp2f(pose - OFFE);
    row_loss = LOGIT_MAX + 0.69314718f * (__log2f(ssum) - pose);
  }
  __shared__ float bl[16];
  if (l == 0) bl[tid >> 4] = row_loss;
  __syncthreads();
  if (tid == 0) {
    float s = 0.f;
#pragma unroll
    for (int i = 0; i < 16; ++i) s += bl[i];
    atomicAdd(&acc[kk], s);
  }
}

__global__ void finalize_kernel(const float* __restrict__ acc,
                                float* __restrict__ out) {
  if (threadIdx.x == 0) {
    float tot = 0.f;
#pragma unroll
    for (int kk = 0; kk < 12; ++kk) tot += acc[kk] / (8.0f * (255 - kk));
    out[0] = tot / 12.0f;
  }
}

extern "C" void kernel_launch(void* const* d_in, const int* in_sizes, int n_in,
                              void* d_out, int out_size, void* d_ws, size_t ws_size,
                              hipStream_t stream) {
  const float* ctx = (const float*)d_in[0];   // (8,256,512)
  const float* enc = (const float*)d_in[1];   // (8,256,256)
  const float* W   = (const float*)d_in[2];   // (12,256,512)
  const int*   neg = (const int*)d_in[3];     // (12,2040,128)
  float* out = (float*)d_out;

  char* ws = (char*)d_ws;
  uint*   pool4 = (uint*)(ws);                      // 2048*128 B = 262,144
  ushort* ctxb  = (ushort*)(ws + 262144);           // 2,097,152
  ushort* Wb    = (ushort*)(ws + 2359296);          // 3,145,728
  uint*   Zp    = (uint*)(ws + 5505024);            // 12,533,760
  float*  accb  = (float*)(ws + 18038784);          // 48 B

  cvt_bf16_kernel<<<dim3(1280), dim3(256), 0, stream>>>(ctx, W, ctxb, Wb);
  pool_norm_kernel<<<dim3(128), dim3(256), 0, stream>>>(enc, pool4, accb);
  zhat_gemm_kernel<<<dim3(2, 32, 12), dim3(256), 0, stream>>>(ctxb, Wb, Zp);
  loss_kernel<<<dim3(128, 12), dim3(256), 0, stream>>>(Zp, pool4, neg, accb);
  finalize_kernel<<<dim3(1), dim3(64), 0, stream>>>(accb, out);
}

// Round 11
// 66.356 us; speedup vs baseline: 1.1045x; 1.0427x over previous
//
#include <hip/hip_runtime.h>
#include <hip/hip_bf16.h>

typedef __attribute__((ext_vector_type(8))) short short8;
typedef __attribute__((ext_vector_type(4))) float f32x4;
typedef _Float16 __attribute__((ext_vector_type(2))) half2v;

#define INV_TEMP 14.285714285714286f
#define LOGIT_MAX 14.2857143f
#define L2E 1.44269504f
#define OFFE (LOGIT_MAX * L2E)
#define PCLIP 0.23f
#define PDELTA (PCLIP / 7.f)
#define PQS (7.f / PCLIP)

__device__ __forceinline__ ushort bf16c(float f) {
  uint u = __float_as_uint(f);
  uint r = (u + 0x7fffu + ((u >> 16) & 1u)) >> 16;
  return (ushort)r;
}
__device__ __forceinline__ uint pk2(float a, float b) {
  return (uint)bf16c(a) | ((uint)bf16c(b) << 16);
}
__device__ __forceinline__ uint pkh(float a, float b) {
  return __builtin_bit_cast(uint, __builtin_amdgcn_cvt_pkrtz(a, b));
}
__device__ __forceinline__ half2v h2(uint u) {
  return __builtin_bit_cast(half2v, u);
}
__device__ __forceinline__ int sdot4_(uint a, uint b, int c) {
  return __builtin_amdgcn_sdot4((int)a, (int)b, c, false);
}
// async global->LDS, 16B per lane; LDS dest = wave-uniform base + lane*16
__device__ __forceinline__ void gl_lds16(const void* g, void* l) {
  __builtin_amdgcn_global_load_lds(
      (const __attribute__((address_space(1))) void*)g,
      (__attribute__((address_space(3))) void*)l, 16, 0, 0);
}

template <int CTRL>
__device__ __forceinline__ float dpp_add(float v) {
  const int x = __builtin_amdgcn_mov_dpp(__float_as_int(v), CTRL, 0xF, 0xF, true);
  return v + __int_as_float(x);
}
template <int CTRL>
__device__ __forceinline__ int dpp_addi(int v) {
  return v + __builtin_amdgcn_mov_dpp(v, CTRL, 0xF, 0xF, true);
}
__device__ __forceinline__ float qsum16(float v) {
  v = dpp_add<0xB1>(v);
  v = dpp_add<0x4E>(v);
  v = dpp_add<0x141>(v);
  v = dpp_add<0x140>(v);
  return v;
}
__device__ __forceinline__ int qsum8i(int v) {
  v = dpp_addi<0xB1>(v);
  v = dpp_addi<0x4E>(v);
  v = dpp_addi<0x141>(v);
  return v;
}

// ---------- prep: cvt ctx (blocks [0,512)), cvt W ([512,1280)), pool int4 ([1280,1408)) ----------
__global__ __launch_bounds__(256) void prep_kernel(
    const float* __restrict__ ctx, const float* __restrict__ W,
    const float* __restrict__ enc, ushort* __restrict__ ctxb,
    ushort* __restrict__ Wb, uint* __restrict__ pool4,
    float* __restrict__ acc) {
  const int bid = blockIdx.x;
  const int tid = threadIdx.x;
  if (bid < 1280) {
    const float* in;
    ushort* out;
    size_t i;
    if (bid < 512) { in = ctx; out = ctxb; i = (size_t)bid * 256 + tid; }
    else           { in = W;   out = Wb;   i = (size_t)(bid - 512) * 256 + tid; }
    const float4 a = *(const float4*)(in + i * 8);
    const float4 b = *(const float4*)(in + i * 8 + 4);
    const uint4 o = make_uint4(pk2(a.x, a.y), pk2(a.z, a.w), pk2(b.x, b.y), pk2(b.z, b.w));
    *(uint4*)(out + i * 8) = o;
    return;
  }
  // pool: p' = clamp(rint(e_norm/PDELTA),-7,7)+8, nibble n of uint j = chan 8j+n
  if (bid == 1280 && tid < 12) acc[tid] = 0.f;
  const int grp = tid >> 4, lane = tid & 15;
  const int r = (bid - 1280) * 16 + grp;  // 0..2047
  const float* src = enc + (size_t)r * 256 + lane * 16;
  float4 v0 = *(const float4*)(src);
  float4 v1 = *(const float4*)(src + 4);
  float4 v2 = *(const float4*)(src + 8);
  float4 v3 = *(const float4*)(src + 12);
  float c[16] = {v0.x, v0.y, v0.z, v0.w, v1.x, v1.y, v1.z, v1.w,
                 v2.x, v2.y, v2.z, v2.w, v3.x, v3.y, v3.z, v3.w};
  float ss = 0.f;
#pragma unroll
  for (int i = 0; i < 16; ++i) ss = fmaf(c[i], c[i], ss);
  ss = qsum16(ss);
  const float qs = rsqrtf(ss) * PQS;
  uint w0 = 0, w1 = 0;
#pragma unroll
  for (int n = 0; n < 8; ++n) {
    const int q0 = (int)rintf(fminf(fmaxf(c[n] * qs, -7.f), 7.f)) + 8;
    const int q1 = (int)rintf(fminf(fmaxf(c[8 + n] * qs, -7.f), 7.f)) + 8;
    w0 |= (uint)q0 << (4 * n);
    w1 |= (uint)q1 << (4 * n);
  }
  *(uint2*)(pool4 + (size_t)r * 32 + lane * 2) = make_uint2(w0, w1);
}

// ---------- z_hat[k] = ctx_rows @ W[k]^T, bf16 MFMA, global_load_lds staging ----------
// LDS layout: seg s (16B) at offset s*16; A: s = (kseg<<6)|row (64 rows, kseg 0..3);
// B: s = (kseg<<7)|row (128 rows). Fragment read = ds_read_b128 at (l16*R + row)*16.
__global__ __launch_bounds__(256) void zhat_gemm_kernel(
    const ushort* __restrict__ ctxb, const ushort* __restrict__ Wb,
    uint* __restrict__ Zp) {
  const int kk = blockIdx.z;
  const int Tk = 255 - kk, Nk = 8 * Tk;
  const int rowbase = blockIdx.y * 64;
  if (rowbase >= Nk) return;
  const int colbase = blockIdx.x * 128;

  __shared__ __attribute__((aligned(16))) ushort As[64 * 32];    // 4 KB
  __shared__ __attribute__((aligned(16))) ushort Bs[128 * 32];   // 8 KB

  const int tid = threadIdx.x;
  const int wid = tid >> 6, lane = tid & 63;
  // A stage: seg t -> row t&63, k-oct t>>6
  const int arow = tid & 63;
  const int akseg = (tid >> 6) * 8;
  int n = rowbase + arow;
  if (n >= Nk) n = Nk - 1;  // clamp (valid memory; result rows discarded)
  const int bb = n / Tk, tt = n - bb * Tk;
  const ushort* aptr = ctxb + ((size_t)(bb * 256 + tt)) * 512 + akseg;
  // B stage: seg t -> row t&127, k-oct t>>7; second seg t+256 -> same row, k-oct+2
  const int brow = tid & 127;
  const int bke = (tid >> 7) * 8;
  const ushort* bptr = Wb + ((size_t)kk * 256 + colbase + brow) * 512 + bke;

  char* As_w = (char*)As + wid * 1024;
  char* Bs_w = (char*)Bs + wid * 1024;

  const int wm = wid >> 1, wn = wid & 1;
  const int l15 = lane & 15, l16 = lane >> 4;

  f32x4 acc[2][4];
#pragma unroll
  for (int i = 0; i < 2; ++i)
#pragma unroll
    for (int j = 0; j < 4; ++j) acc[i][j] = (f32x4){0.f, 0.f, 0.f, 0.f};

  // fragment read bases (ushort offsets; seg byte addr = (l16*R + row)*16)
  const ushort* aread = As + (size_t)(l16 * 64 + wm * 32 + l15) * 8;
  const ushort* bread = Bs + (size_t)(l16 * 128 + wn * 64 + l15) * 8;

  for (int k0 = 0; k0 < 512; k0 += 32) {
    __syncthreads();  // previous step's readers done
    gl_lds16(aptr + k0, As_w);
    gl_lds16(bptr + k0, Bs_w);
    gl_lds16(bptr + k0 + 16, Bs_w + 4096);
    __syncthreads();  // loads landed (compiler drains vmcnt before barrier)
    short8 bf[4];
#pragma unroll
    for (int nb = 0; nb < 4; ++nb) bf[nb] = *(const short8*)(bread + (size_t)nb * 16 * 8);
#pragma unroll
    for (int mb = 0; mb < 2; ++mb) {
      short8 af = *(const short8*)(aread + (size_t)mb * 16 * 8);
#pragma unroll
      for (int nb = 0; nb < 4; ++nb)
        acc[mb][nb] = __builtin_amdgcn_mfma_f32_16x16x32_bf16(af, bf[nb], acc[mb][nb], 0, 0, 0);
    }
  }

  // uint u of row holds chans (32*(u>>4)+(u&15), +16)
#pragma unroll
  for (int mb = 0; mb < 2; ++mb) {
    const int row0 = rowbase + wm * 32 + mb * 16 + l16 * 4;
#pragma unroll
    for (int r = 0; r < 4; ++r) {
      const int row = row0 + r;
      if (row < Nk) {
        uint* zp = Zp + ((size_t)kk * 2040 + row) * 128 + (colbase >> 1) + wn * 32 + l15;
        zp[0]  = pkh(acc[mb][0][r], acc[mb][1][r]);
        zp[16] = pkh(acc[mb][2][r], acc[mb][3][r]);
      }
    }
  }
}

// ---------- loss: 16 lanes/row = 2 neg-halves x 8 chan-lanes; int8 z · int4 pool ----------
#define DOTN(P) ({                                                              \
    int d0_ = 0, d1_ = 0;                                                       \
    uint e_, o_;                                                                \
    e_ = P.x & 0x0F0F0F0Fu; o_ = (P.x >> 4) & 0x0F0F0F0Fu;                      \
    d0_ = sdot4_(zq[0], e_, d0_); d1_ = sdot4_(zq[4], o_, d1_);                 \
    e_ = P.y & 0x0F0F0F0Fu; o_ = (P.y >> 4) & 0x0F0F0F0Fu;                      \
    d0_ = sdot4_(zq[1], e_, d0_); d1_ = sdot4_(zq[5], o_, d1_);                 \
    e_ = P.z & 0x0F0F0F0Fu; o_ = (P.z >> 4) & 0x0F0F0F0Fu;                      \
    d0_ = sdot4_(zq[2], e_, d0_); d1_ = sdot4_(zq[6], o_, d1_);                 \
    e_ = P.w & 0x0F0F0F0Fu; o_ = (P.w >> 4) & 0x0F0F0F0Fu;                      \
    d0_ = sdot4_(zq[3], e_, d0_); d1_ = sdot4_(zq[7], o_, d1_);                 \
    qsum8i(d0_ + d1_); })

#define LDB(P, IDX) P = *(const uint4*)(pbase + (size_t)(uint)(IDX) * 32);
#define ACCB(SUM, P) SUM += exp2f(fmaf((float)DOTN(P), kG, c2m));

__global__ __launch_bounds__(256) void loss_kernel(
    const uint* __restrict__ Zp, const uint* __restrict__ pool4,
    const int* __restrict__ neg_idx, float* __restrict__ acc) {
  const int kk = blockIdx.y;
  const int Tk = 255 - kk, Nk = 8 * Tk;
  if ((int)(blockIdx.x * 16) >= Nk) return;
  const int tid = threadIdx.x;
  const int n = blockIdx.x * 16 + (tid >> 4);
  const int l = tid & 15;
  const int h = l >> 3;   // neg half: negs [64h, 64h+64)
  const int g = l & 7;    // chan chunk: chans [32g, 32g+32)
  float row_loss = 0.f;
  if (n < Nk) {
    const uint* zr = Zp + ((size_t)kk * 2040 + n) * 128 + g * 16;
    uint zu[16];
#pragma unroll
    for (int i = 0; i < 4; ++i) *(uint4*)(zu + 4 * i) = *(const uint4*)(zr + 4 * i);
    float zf[32];
#pragma unroll
    for (int c = 0; c < 16; ++c) {
      const half2v hv = h2(zu[c]);
      zf[c] = (float)hv.x;
      zf[16 + c] = (float)hv.y;
    }
    float ss = 0.f;
#pragma unroll
    for (int i = 0; i < 32; ++i) ss = fmaf(zf[i], zf[i], ss);
    ss = dpp_add<0xB1>(ss); ss = dpp_add<0x4E>(ss); ss = dpp_add<0x141>(ss);
    const float s127 = rsqrtf(ss) * 127.f;
    uint zq[8];
#pragma unroll
    for (int t = 0; t < 4; ++t) {
      const uint e0 = (uint)((int)rintf(zf[8 * t]     * s127) & 255);
      const uint e1 = (uint)((int)rintf(zf[8 * t + 2] * s127) & 255);
      const uint e2 = (uint)((int)rintf(zf[8 * t + 4] * s127) & 255);
      const uint e3 = (uint)((int)rintf(zf[8 * t + 6] * s127) & 255);
      zq[t] = e0 | (e1 << 8) | (e2 << 16) | (e3 << 24);
      const uint o0 = (uint)((int)rintf(zf[8 * t + 1] * s127) & 255);
      const uint o1 = (uint)((int)rintf(zf[8 * t + 3] * s127) & 255);
      const uint o2 = (uint)((int)rintf(zf[8 * t + 5] * s127) & 255);
      const uint o3 = (uint)((int)rintf(zf[8 * t + 7] * s127) & 255);
      zq[t + 4] = o0 | (o1 << 8) | (o2 << 16) | (o3 << 24);
    }
    int nq = 0, zs = 0;
#pragma unroll
    for (int t = 0; t < 8; ++t) {
      nq = sdot4_(zq[t], zq[t], nq);
      zs = sdot4_(zq[t], 0x01010101u, zs);
    }
    nq = qsum8i(nq);
    zs = qsum8i(zs);
    const float kG = (INV_TEMP * L2E * PDELTA) * rsqrtf((float)nq);
    const float c2 = -8.f * (float)zs * kG;
    const float c2m = c2 - OFFE;

    const uint* pbase = pool4 + g * 4;
    const int bb = n / Tk, tt = n - bb * Tk;
    uint4 PP;
    LDB(PP, bb * 256 + tt + kk + 1)
    const float pose = fmaf((float)DOTN(PP), kG, c2);

    const int* ip = neg_idx + ((size_t)kk * 2040 + n) * 128 + h * 64;
    float s0 = 0.f, s1 = 0.f, s2 = 0.f, s3 = 0.f;
    uint4 A, B, C, D, E, F, G, H;
    {
      const int4 iv = *(const int4*)ip;
      LDB(A, iv.x) LDB(B, iv.y) LDB(C, iv.z) LDB(D, iv.w)
    }
    for (int j8 = 0; j8 < 8; ++j8) {
      {  // prefetch odd quad
        const int4 jv = *(const int4*)(ip + j8 * 8 + 4);
        LDB(E, jv.x) LDB(F, jv.y) LDB(G, jv.z) LDB(H, jv.w)
      }
      ACCB(s0, A) ACCB(s1, B) ACCB(s2, C) ACCB(s3, D)
      if (j8 < 7) {  // prefetch next even quad
        const int4 kv = *(const int4*)(ip + j8 * 8 + 8);
        LDB(A, kv.x) LDB(B, kv.y) LDB(C, kv.z) LDB(D, kv.w)
      }
      ACCB(s0, E) ACCB(s1, F) ACCB(s2, G) ACCB(s3, H)
    }
    float sl = (s0 + s1) + (s2 + s3);
    sl = dpp_add<0x140>(sl);  // crosses (h,g)<->(1-h,7-g)
    const float ssum = sl + exp2f(pose - OFFE);
    row_loss = LOGIT_MAX + 0.69314718f * (__log2f(ssum) - pose);
  }
  __shared__ float bl[16];
  if (l == 0) bl[tid >> 4] = row_loss;
  __syncthreads();
  if (tid == 0) {
    float s = 0.f;
#pragma unroll
    for (int i = 0; i < 16; ++i) s += bl[i];
    atomicAdd(&acc[kk], s);
  }
}

__global__ void finalize_kernel(const float* __restrict__ acc,
                                float* __restrict__ out) {
  if (threadIdx.x == 0) {
    float tot = 0.f;
#pragma unroll
    for (int kk = 0; kk < 12; ++kk) tot += acc[kk] / (8.0f * (255 - kk));
    out[0] = tot / 12.0f;
  }
}

extern "C" void kernel_launch(void* const* d_in, const int* in_sizes, int n_in,
                              void* d_out, int out_size, void* d_ws, size_t ws_size,
                              hipStream_t stream) {
  const float* ctx = (const float*)d_in[0];   // (8,256,512)
  const float* enc = (const float*)d_in[1];   // (8,256,256)
  const float* W   = (const float*)d_in[2];   // (12,256,512)
  const int*   neg = (const int*)d_in[3];     // (12,2040,128)
  float* out = (float*)d_out;

  char* ws = (char*)d_ws;
  uint*   pool4 = (uint*)(ws);                      // 262,144 B
  ushort* ctxb  = (ushort*)(ws + 262144);           // 2,097,152
  ushort* Wb    = (ushort*)(ws + 2359296);          // 3,145,728
  uint*   Zp    = (uint*)(ws + 5505024);            // 12,533,760
  float*  accb  = (float*)(ws + 18038784);          // 48 B

  prep_kernel<<<dim3(1408), dim3(256), 0, stream>>>(ctx, W, enc, ctxb, Wb, pool4, accb);
  zhat_gemm_kernel<<<dim3(2, 32, 12), dim3(256), 0, stream>>>(ctxb, Wb, Zp);
  loss_kernel<<<dim3(128, 12), dim3(256), 0, stream>>>(Zp, pool4, neg, accb);
  finalize_kernel<<<dim3(1), dim3(64), 0, stream>>>(accb, out);
}